// Round 3
// baseline (373.569 us; speedup 1.0000x reference)
//
#include <hip/hip_runtime.h>
#include <math.h>

#define B_ 8
#define S_ 2048
#define D_ 512
#define HSZ (B_ * S_ * D_)   // 8,388,608 elements

typedef _Float16 half8 __attribute__((ext_vector_type(8)));
typedef _Float16 half4h __attribute__((ext_vector_type(4)));
typedef __fp16 fp16x2 __attribute__((ext_vector_type(2)));
typedef float f32x4 __attribute__((ext_vector_type(4)));
typedef float f32x16 __attribute__((ext_vector_type(16)));
typedef unsigned int u32;

constexpr float INV_SCALE = 0.044194173824159216f; // 1/sqrt(512)

__device__ __forceinline__ u32 pk16(float a, float b) {
    fp16x2 r = __builtin_amdgcn_cvt_pkrtz(a, b);
    union { fp16x2 h; u32 u; } U; U.h = r; return U.u;
}

// ================= cvt_all: fp16 convert + tiled transposes =================
__global__ __launch_bounds__(256) void cvt_all(const float* __restrict__ x,
                                               const float* __restrict__ W,
                                               _Float16* __restrict__ xh,
                                               _Float16* __restrict__ xhT,
                                               _Float16* __restrict__ WhT) {
    __shared__ float T[64 * 65];
    const int tid = threadIdx.x;
    const int blk = blockIdx.x;

    const float* src;
    _Float16* dstT;
    _Float16* dstL;
    int t0, d0, dstTld;
    if (blk < 2048) {
        int b = blk >> 8;
        int r = blk & 255;
        t0 = (r >> 3) * 64; d0 = (r & 7) * 64;
        src = x + (size_t)b * (S_ * D_);
        dstT = xhT + (size_t)b * (S_ * D_); dstTld = S_;
        dstL = xh + (size_t)b * (S_ * D_);
    } else {
        int r = blk - 2048;
        t0 = (r >> 3) * 64; d0 = (r & 7) * 64;
        src = W; dstT = WhT; dstTld = 512; dstL = nullptr;
    }

#pragma unroll
    for (int it = 0; it < 4; ++it) {
        int flat = it * 256 + tid;
        int row = flat >> 4, c4 = (flat & 15) * 4;
        float4 v = *(const float4*)(src + (size_t)(t0 + row) * 512 + d0 + c4);
        T[row * 65 + c4 + 0] = v.x; T[row * 65 + c4 + 1] = v.y;
        T[row * 65 + c4 + 2] = v.z; T[row * 65 + c4 + 3] = v.w;
        if (dstL) {
            half4h h = { (_Float16)v.x, (_Float16)v.y, (_Float16)v.z, (_Float16)v.w };
            *(half4h*)(dstL + (size_t)(t0 + row) * 512 + d0 + c4) = h;
        }
    }
    __syncthreads();
#pragma unroll
    for (int it = 0; it < 2; ++it) {
        int flat = it * 256 + tid;
        int d = flat >> 3, c = (flat & 7) * 8;
        half8 hv;
#pragma unroll
        for (int j = 0; j < 8; ++j) hv[j] = (_Float16)T[(c + j) * 65 + d];
        *(half8*)(dstT + (size_t)(d0 + d) * dstTld + t0 + c) = hv;
    }
}

// ================= MFMA GEMM: qwh = fp16( (xh @ W) * inv_scale ) =============
__global__ __launch_bounds__(256, 2) void gemm_h(const _Float16* __restrict__ xh,
                                                 const _Float16* __restrict__ WhT,
                                                 _Float16* __restrict__ qwh) {
    const int tid = threadIdx.x;
    const int w = tid >> 6, lane = tid & 63, quad = lane >> 4, l16 = lane & 15;
    const int n0 = (blockIdx.x & 3) * 128 + w * 32;
    const int m0 = (blockIdx.x >> 2) * 128;

    half8 Bf[16][2];
#pragma unroll
    for (int kc = 0; kc < 16; ++kc)
#pragma unroll
        for (int nt = 0; nt < 2; ++nt)
            Bf[kc][nt] = *(const half8*)(WhT + (size_t)(n0 + nt * 16 + l16) * 512 + kc * 32 + quad * 8);

    f32x4 acc[8][2];
#pragma unroll
    for (int mt = 0; mt < 8; ++mt)
#pragma unroll
        for (int nt = 0; nt < 2; ++nt) acc[mt][nt] = (f32x4){0.f, 0.f, 0.f, 0.f};

#pragma unroll
    for (int mt = 0; mt < 8; ++mt) {
        const _Float16* arow = xh + (size_t)(m0 + mt * 16 + l16) * 512 + quad * 8;
#pragma unroll
        for (int h = 0; h < 2; ++h) {
            half8 Af[8];
#pragma unroll
            for (int k8 = 0; k8 < 8; ++k8)
                Af[k8] = *(const half8*)(arow + (h * 8 + k8) * 32);
#pragma unroll
            for (int k8 = 0; k8 < 8; ++k8) {
                acc[mt][0] = __builtin_amdgcn_mfma_f32_16x16x32_f16(Af[k8], Bf[h * 8 + k8][0], acc[mt][0], 0, 0, 0);
                acc[mt][1] = __builtin_amdgcn_mfma_f32_16x16x32_f16(Af[k8], Bf[h * 8 + k8][1], acc[mt][1], 0, 0, 0);
            }
        }
    }
#pragma unroll
    for (int mt = 0; mt < 8; ++mt)
#pragma unroll
        for (int nt = 0; nt < 2; ++nt)
#pragma unroll
            for (int r = 0; r < 4; ++r)
                qwh[(size_t)(m0 + mt * 16 + quad * 4 + r) * 512 + n0 + nt * 16 + l16] =
                    (_Float16)(acc[mt][nt][r] * INV_SCALE);
}

// ================= flash7: no K LDS, r=1 QK, 4-way exchange =================
// 4 waves, TQ=32, TK=32, 512 blocks (b = bx&7 one batch per XCD).
// Wave w: k-quarter w*128 of QK (Qr 8 frags) + d-range w*128 of PV.
// K A-frags DIRECT from global (L2-resident), prefetched 1 tile ahead into a
// register ping-pong (Ka/Kb2, 2x-unrolled loop). V A-frags loaded current-tile
// (land during QK+barrier+softmax). S partials exchanged via double-buffered
// contiguous LDS (zero bank conflicts), summed 4-way. ONE barrier per tile.
// Softmax lane-local (defer-max THR=8); P rebuilt via cvt_pkrtz + shfl_xor32.
__global__ __launch_bounds__(256, 2)
void flash7(const _Float16* __restrict__ xh, const _Float16* __restrict__ xhT,
            const _Float16* __restrict__ qwh, float* __restrict__ out) {
    // Sx: [2 phase][4 wave][1024 f32] = 32 KB; epilogue overlays 67.6 KB.
    __shared__ __align__(16) unsigned char SMEM[69632];
    float* Sx = (float*)SMEM;

    const int tid = threadIdx.x;
    const int w = tid >> 6, lane = tid & 63;
    const int r31 = lane & 31, hi = lane >> 5;
    const int d0w = w * 128;                 // PV d-range
    const int kq = w * 128;                  // QK k-quarter (halves)
    const int bx = blockIdx.x;
    const int b = bx & 7;
    const int q0 = (bx >> 3) * 32;
    const size_t xb = (size_t)b * (S_ * D_);

    // Q B-frags for this wave's k-quarter (col=q=lane&31, k=kq+kc*16+hi*8).
    half8 Qr[8];
#pragma unroll
    for (int kc = 0; kc < 8; ++kc)
        Qr[kc] = *(const half8*)(qwh + xb + (size_t)(q0 + r31) * 512 + kq + kc * 16 + hi * 8);

    const _Float16* kbase = xh + xb + kq + hi * 8;                    // + t*512 + kc*16
    const _Float16* vbase = xhT + xb + (size_t)(d0w + r31) * S_ + hi * 8; // + dc*32*S_ + t0 + kh*16

    // Prologue: K frags for tile 0.
    half8 Ka[8], Kb2[8];
#pragma unroll
    for (int kc = 0; kc < 8; ++kc)
        Ka[kc] = *(const half8*)(kbase + (size_t)r31 * 512 + kc * 16);

    f32x16 O[4];
#pragma unroll
    for (int dc = 0; dc < 4; ++dc)
#pragma unroll
        for (int r = 0; r < 16; ++r) O[dc][r] = 0.f;
    float m = -1e30f, l = 0.f;

#define FBODY(TI, KC, KN) do {                                                  \
    const int t0_ = (TI) * 32;                                                  \
    const int tn_ = (((TI) + 1) & 63) * 32;                                     \
    const int p_ = (TI) & 1;                                                    \
    /* current-tile V^T A-frags (global, L2) — consumed at PV far below */      \
    half8 Vc[8];                                                                \
    _Pragma("unroll") for (int dc = 0; dc < 4; ++dc)                            \
    _Pragma("unroll") for (int kh = 0; kh < 2; ++kh)                            \
        Vc[dc * 2 + kh] = *(const half8*)(vbase + (size_t)(dc * 32) * S_ + t0_ + kh * 16); \
    /* QK partial (k-quarter): 8 MFMA, 2 chains */                              \
    f32x16 sa, sb;                                                              \
    _Pragma("unroll") for (int r = 0; r < 16; ++r) { sa[r] = 0.f; sb[r] = 0.f; }\
    _Pragma("unroll") for (int kc = 0; kc < 8; kc += 2) {                       \
        sa = __builtin_amdgcn_mfma_f32_32x32x16_f16(KC[kc],     Qr[kc],     sa, 0, 0, 0); \
        sb = __builtin_amdgcn_mfma_f32_32x32x16_f16(KC[kc + 1], Qr[kc + 1], sb, 0, 0, 0); \
    }                                                                           \
    /* prefetch next tile's K frags (consumed next FBODY) */                    \
    _Pragma("unroll") for (int kc = 0; kc < 8; ++kc)                            \
        KN[kc] = *(const half8*)(kbase + (size_t)(tn_ + r31) * 512 + kc * 16);  \
    f32x16 sS = sa + sb;                                                        \
    /* write partial S: contiguous 1024B per instr — conflict-free */           \
    {                                                                           \
        float* sxw = Sx + (p_ * 4 + w) * 1024;                                  \
        _Pragma("unroll") for (int r2 = 0; r2 < 4; ++r2) {                      \
            f32x4 v_ = { sS[4 * r2 + 0], sS[4 * r2 + 1], sS[4 * r2 + 2], sS[4 * r2 + 3] }; \
            *(f32x4*)&sxw[(r2 * 64 + lane) * 4] = v_;                           \
        }                                                                       \
    }                                                                           \
    __syncthreads();  /* the ONLY barrier: partials visible */                  \
    /* 4-way sum */                                                             \
    float sv[16];                                                               \
    _Pragma("unroll") for (int i = 0; i < 16; ++i) sv[i] = sS[i];               \
    _Pragma("unroll") for (int pw = 1; pw < 4; ++pw) {                          \
        const float* sxp = Sx + (p_ * 4 + (w ^ pw)) * 1024;                     \
        _Pragma("unroll") for (int r2 = 0; r2 < 4; ++r2) {                      \
            f32x4 pp = *(const f32x4*)&sxp[(r2 * 64 + lane) * 4];               \
            _Pragma("unroll") for (int j = 0; j < 4; ++j) sv[4 * r2 + j] += pp[j]; \
        }                                                                       \
    }                                                                           \
    /* lane-local online softmax (defer-max THR=8) */                           \
    float mt_ = sv[0];                                                          \
    _Pragma("unroll") for (int i = 1; i < 16; ++i) mt_ = fmaxf(mt_, sv[i]);     \
    mt_ = fmaxf(mt_, __shfl_xor(mt_, 32));                                      \
    if (__any(mt_ > m + 8.f)) {                                                 \
        float mn = fmaxf(m, mt_);                                               \
        float a_ = __expf(m - mn);                                              \
        l *= a_;                                                                \
        _Pragma("unroll") for (int dc = 0; dc < 4; ++dc)                        \
        _Pragma("unroll") for (int r = 0; r < 16; ++r) O[dc][r] *= a_;          \
        m = mn;                                                                 \
    }                                                                           \
    float pa[16]; float rs = 0.f;                                               \
    _Pragma("unroll") for (int i = 0; i < 16; ++i) { pa[i] = __expf(sv[i] - m); rs += pa[i]; } \
    l += rs + __shfl_xor(rs, 32);                                               \
    /* build PV B-frags: P[q][t=16kh+8hi+j] via cvt_pk + shfl_xor32 */          \
    u32 q16[8];                                                                 \
    _Pragma("unroll") for (int r2 = 0; r2 < 4; ++r2) {                          \
        q16[2 * r2 + 0] = pk16(pa[4 * r2 + 0], pa[4 * r2 + 1]);                 \
        q16[2 * r2 + 1] = pk16(pa[4 * r2 + 2], pa[4 * r2 + 3]);                 \
    }                                                                           \
    half8 Pf[2];                                                                \
    _Pragma("unroll") for (int kh = 0; kh < 2; ++kh) {                          \
        int r2o = 2 * kh + hi, r2s = 2 * kh + (hi ^ 1);                         \
        u32 rv0 = (u32)__shfl_xor((int)q16[2 * r2s + 0], 32);                   \
        u32 rv1 = (u32)__shfl_xor((int)q16[2 * r2s + 1], 32);                   \
        u32 o0 = q16[2 * r2o + 0], o1 = q16[2 * r2o + 1];                       \
        union { u32 u[4]; half8 v; } U_;                                        \
        U_.u[0] = hi ? rv0 : o0; U_.u[1] = hi ? rv1 : o1;                       \
        U_.u[2] = hi ? o0 : rv0; U_.u[3] = hi ? o1 : rv1;                       \
        Pf[kh] = U_.v;                                                          \
    }                                                                           \
    /* PV: O^T[d,q] += V^T x P^T */                                             \
    _Pragma("unroll") for (int dc = 0; dc < 4; ++dc) {                          \
        O[dc] = __builtin_amdgcn_mfma_f32_32x32x16_f16(Vc[dc * 2 + 0], Pf[0], O[dc], 0, 0, 0); \
        O[dc] = __builtin_amdgcn_mfma_f32_32x32x16_f16(Vc[dc * 2 + 1], Pf[1], O[dc], 0, 0, 0); \
    }                                                                           \
} while (0)

    for (int tp = 0; tp < 32; ++tp) {
        FBODY(2 * tp,     Ka,  Kb2);
        FBODY(2 * tp + 1, Kb2, Ka);
    }
#undef FBODY

    __syncthreads();   // protect Sx region before epilogue overlay

    // ---- epilogue: O^T/l -> LDS transpose -> coalesced f32x4 stores ----
    {
        float inv = 1.0f / l;
        float* ew = (float*)SMEM + w * 4224;   // 32 rows x 132 (pad) per wave
#pragma unroll
        for (int dc = 0; dc < 4; ++dc)
#pragma unroll
            for (int r = 0; r < 16; ++r) {
                int dl = dc * 32 + (r & 3) + ((r >> 2) << 3) + (hi << 2);
                ew[r31 * 132 + dl] = O[dc][r] * inv;
            }
#pragma unroll
        for (int j = 0; j < 4; ++j) {
            int flat = j * 64 + lane;
            int qq = flat >> 3, c16 = (flat & 7) << 4;
            float* gp = out + xb + (size_t)(q0 + qq) * 512 + d0w + c16;
#pragma unroll
            for (int k = 0; k < 4; ++k)
                *(f32x4*)(gp + k * 4) = *(const f32x4*)&ew[qq * 132 + c16 + k * 4];
        }
    }
}

// ================= fp32 fallback (round 1) ==================================
__global__ __launch_bounds__(256) void xw_gemm_f32(const float* __restrict__ A,
                                                   const float* __restrict__ W,
                                                   float* __restrict__ C) {
    __shared__ float As[16][65];
    __shared__ float Bs[16][64];
    const int tid = threadIdx.x;
    const int row0 = blockIdx.y * 64, col0 = blockIdx.x * 64;
    const int ty = tid / 16, tx = tid % 16;
    float acc[4][4] = {};
    const int ar = tid / 4, ak = (tid % 4) * 4, bk = tid / 16, bn = (tid % 16) * 4;
    for (int k0 = 0; k0 < 512; k0 += 16) {
        float4 a4 = *(const float4*)(A + (size_t)(row0 + ar) * 512 + k0 + ak);
        float4 b4 = *(const float4*)(W + (size_t)(k0 + bk) * 512 + col0 + bn);
        __syncthreads();
        As[ak + 0][ar] = a4.x; As[ak + 1][ar] = a4.y;
        As[ak + 2][ar] = a4.z; As[ak + 3][ar] = a4.w;
        *(float4*)&Bs[bk][bn] = b4;
        __syncthreads();
#pragma unroll
        for (int kk = 0; kk < 16; kk++) {
            float a[4], bv[4];
#pragma unroll
            for (int i = 0; i < 4; i++) a[i] = As[kk][ty * 4 + i];
#pragma unroll
            for (int j = 0; j < 4; j++) bv[j] = Bs[kk][tx * 4 + j];
#pragma unroll
            for (int i = 0; i < 4; i++)
#pragma unroll
                for (int j = 0; j < 4; j++) acc[i][j] += a[i] * bv[j];
        }
    }
#pragma unroll
    for (int i = 0; i < 4; i++) {
        float4 o = make_float4(acc[i][0] * INV_SCALE, acc[i][1] * INV_SCALE,
                               acc[i][2] * INV_SCALE, acc[i][3] * INV_SCALE);
        *(float4*)(C + (size_t)(row0 + ty * 4 + i) * 512 + col0 + tx * 4) = o;
    }
}

__global__ __launch_bounds__(256) void flash_f32(const float* __restrict__ x,
                                                 const float* __restrict__ qw,
                                                 float* __restrict__ out) {
    __shared__ float4 kt[16 * 136];
    const int tid = threadIdx.x;
    const int q = tid >> 3, g = tid & 7;
    const int blk = blockIdx.x;
    const int b = blk >> 6;
    const int qrow = (blk & 63) * 32 + q;
    const size_t xbase = (size_t)b * S_ * D_;
    float qwr[64];
    {
        const float4* p = (const float4*)(qw + xbase + (size_t)qrow * D_ + g * 64);
#pragma unroll
        for (int i4 = 0; i4 < 16; i4++) {
            float4 v = p[i4];
            qwr[4 * i4 + 0] = v.x; qwr[4 * i4 + 1] = v.y;
            qwr[4 * i4 + 2] = v.z; qwr[4 * i4 + 3] = v.w;
        }
    }
    float oa[64];
#pragma unroll
    for (int i = 0; i < 64; i++) oa[i] = 0.f;
    float m = -1e30f, l = 0.f;
    const float4* x4 = (const float4*)(x + xbase);
    for (int t0 = 0; t0 < S_; t0 += 16) {
        __syncthreads();
#pragma unroll
        for (int j = 0; j < 8; j++) {
            int f = tid + j * 256;
            int tt = f >> 7, c = f & 127;
            kt[tt * 136 + (c >> 4) * 17 + (c & 15)] = x4[(size_t)(t0 + tt) * 128 + c];
        }
        __syncthreads();
#pragma unroll 1
        for (int tt = 0; tt < 16; tt++) {
            float4 kv[16];
            const float4* kp = &kt[tt * 136 + g * 17];
#pragma unroll
            for (int i4 = 0; i4 < 16; i4++) kv[i4] = kp[i4];
            float s = 0.f;
#pragma unroll
            for (int i4 = 0; i4 < 16; i4++)
                s += qwr[4 * i4] * kv[i4].x + qwr[4 * i4 + 1] * kv[i4].y
                   + qwr[4 * i4 + 2] * kv[i4].z + qwr[4 * i4 + 3] * kv[i4].w;
            s += __shfl_xor(s, 1, 64); s += __shfl_xor(s, 2, 64); s += __shfl_xor(s, 4, 64);
            if (s > m) {
                float alpha = __expf(m - s);
                l *= alpha;
#pragma unroll
                for (int i = 0; i < 64; i++) oa[i] *= alpha;
                m = s;
            }
            float p = __expf(s - m);
            l += p;
#pragma unroll
            for (int i4 = 0; i4 < 16; i4++) {
                oa[4 * i4 + 0] += p * kv[i4].x; oa[4 * i4 + 1] += p * kv[i4].y;
                oa[4 * i4 + 2] += p * kv[i4].z; oa[4 * i4 + 3] += p * kv[i4].w;
            }
        }
    }
    float inv_l = 1.0f / l;
    float4* op = (float4*)(out + xbase + (size_t)qrow * D_ + g * 64);
#pragma unroll
    for (int i4 = 0; i4 < 16; i4++)
        op[i4] = make_float4(oa[4 * i4] * inv_l, oa[4 * i4 + 1] * inv_l,
                             oa[4 * i4 + 2] * inv_l, oa[4 * i4 + 3] * inv_l);
}

// ================= launch ====================================================
extern "C" void kernel_launch(void* const* d_in, const int* in_sizes, int n_in,
                              void* d_out, int out_size, void* d_ws, size_t ws_size,
                              hipStream_t stream) {
    const float* x = (const float*)d_in[0];
    const float* W = (const float*)d_in[1];
    float* out = (float*)d_out;

    const size_t F16 = (size_t)HSZ * sizeof(_Float16);     // 16,777,216
    const size_t off_qwh = 0;
    const size_t off_xh  = F16;
    const size_t off_xhT = 2 * F16;
    const size_t off_WhT = 3 * F16;
    const size_t base    = 3 * F16 + 512 * 512 * sizeof(_Float16);   // 50,855,936

    if (ws_size >= base) {
        _Float16* qwh = (_Float16*)((char*)d_ws + off_qwh);
        _Float16* xh  = (_Float16*)((char*)d_ws + off_xh);
        _Float16* xhT = (_Float16*)((char*)d_ws + off_xhT);
        _Float16* WhT = (_Float16*)((char*)d_ws + off_WhT);

        cvt_all<<<2112, 256, 0, stream>>>(x, W, xh, xhT, WhT);
        gemm_h<<<512, 256, 0, stream>>>(xh, WhT, qwh);
        flash7<<<512, 256, 0, stream>>>(xh, xhT, qwh, out);
    } else {
        const size_t needf = (size_t)HSZ * sizeof(float);
        float* xw = (ws_size >= needf) ? (float*)d_ws : out;
        dim3 g1(512 / 64, (B_ * S_) / 64);
        xw_gemm_f32<<<g1, 256, 0, stream>>>(x, W, xw);
        flash_f32<<<B_ * (S_ / 32), 256, 0, stream>>>(x, xw, out);
    }
}

// Round 4
// 238.630 us; speedup vs baseline: 1.5655x; 1.5655x over previous
//
#include <hip/hip_runtime.h>
#include <math.h>

#define B_ 8
#define S_ 2048
#define D_ 512
#define HSZ (B_ * S_ * D_)   // 8,388,608 elements

typedef _Float16 half8 __attribute__((ext_vector_type(8)));
typedef _Float16 half4h __attribute__((ext_vector_type(4)));
typedef __fp16 fp16x2 __attribute__((ext_vector_type(2)));
typedef float f32x4 __attribute__((ext_vector_type(4)));
typedef float f32x16 __attribute__((ext_vector_type(16)));
typedef unsigned int u32;

constexpr float INV_SCALE = 0.044194173824159216f; // 1/sqrt(512)

__device__ __forceinline__ u32 pk16(float a, float b) {
    fp16x2 r = __builtin_amdgcn_cvt_pkrtz(a, b);
    union { fp16x2 h; u32 u; } U; U.h = r; return U.u;
}

// ---- frag-tiled layouts (element offsets within one batch) ----
// K/A-frag tiling (also used for qwh/Q): frag(tile=t>>5, w=d>>7, kc=(d>>4)&7)
//   lane (r31=t&31, hi=(d>>3)&1) holds 8 elems j=d&7 -> contiguous 1KB frags.
__device__ __forceinline__ int offK(int t, int d) {
    return ((t >> 5) << 14) | (((d >> 7) & 3) << 12) | (((d >> 4) & 7) << 9) |
           ((t & 31) << 4) | (((d >> 3) & 1) << 3) | (d & 7);
}
// V^T-frag tiling: frag(tile=t>>5, w=d>>7, dc=(d>>5)&3, kh=(t>>4)&1)
//   lane (r31=d&31, hi=(t>>3)&1) holds j=t&7.
__device__ __forceinline__ int offV(int t, int d) {
    return ((t >> 5) << 14) | (((d >> 7) & 3) << 12) | (((d >> 5) & 3) << 10) |
           (((t >> 4) & 1) << 9) | ((d & 31) << 4) | (((t >> 3) & 1) << 3) | (t & 7);
}
// W^T-frag tiling: frag(nt=n>>5, kc=k>>4); lane (r31=n&31, hi=(k>>3)&1), j=k&7.
__device__ __forceinline__ int offWT(int n, int k) {
    return ((n >> 5) << 14) | ((k >> 4) << 9) | ((n & 31) << 4) |
           (((k >> 3) & 1) << 3) | (k & 7);
}

// ================= cvt_all: fp16 convert + frag-tiled emission ==============
__global__ __launch_bounds__(256) void cvt_all(const float* __restrict__ x,
                                               const float* __restrict__ W,
                                               _Float16* __restrict__ xK,
                                               _Float16* __restrict__ xV,
                                               _Float16* __restrict__ WT) {
    __shared__ float T[64 * 65];
    const int tid = threadIdx.x;
    const int blk = blockIdx.x;

    const float* src;
    int t0, d0, isX, bofs = 0;
    if (blk < 2048) {
        int b = blk >> 8;
        int r = blk & 255;
        t0 = (r >> 3) * 64; d0 = (r & 7) * 64;
        src = x + (size_t)b * (S_ * D_);
        bofs = b * (S_ * D_);
        isX = 1;
    } else {
        int r = blk - 2048;
        t0 = (r >> 3) * 64; d0 = (r & 7) * 64;
        src = W;
        isX = 0;
    }

#pragma unroll
    for (int it = 0; it < 4; ++it) {
        int flat = it * 256 + tid;
        int row = flat >> 4, c4 = (flat & 15) * 4;
        float4 v = *(const float4*)(src + (size_t)(t0 + row) * 512 + d0 + c4);
        T[row * 65 + c4 + 0] = v.x; T[row * 65 + c4 + 1] = v.y;
        T[row * 65 + c4 + 2] = v.z; T[row * 65 + c4 + 3] = v.w;
        if (isX) {
            half4h h = { (_Float16)v.x, (_Float16)v.y, (_Float16)v.z, (_Float16)v.w };
            *(half4h*)(xK + bofs + offK(t0 + row, d0 + c4)) = h;
        }
    }
    __syncthreads();
#pragma unroll
    for (int it = 0; it < 2; ++it) {
        int flat = it * 256 + tid;
        int d = flat >> 3, c = (flat & 7) * 8;
        half8 hv;
#pragma unroll
        for (int j = 0; j < 8; ++j) hv[j] = (_Float16)T[(c + j) * 65 + d];
        if (isX)
            *(half8*)(xV + bofs + offV(t0 + c, d0 + d)) = hv;
        else
            *(half8*)(WT + offWT(d0 + d, t0 + c)) = hv;  // W^T[n=d0+d][k=t0+c..+7]
    }
}

// ================= gemm8: qwh = fp16( (x @ W) * inv_scale ), frag-tiled =====
// 512 blocks (2/CU), 4 waves. Block: 128 m-rows x 128 n-cols per... wave w
// owns n-tile n0w=nb*128+w*32 (B resident, 32 frags = 128 VGPR) and loops
// 4 m-tiles of 32 (A streamed 8 frags at a time, contiguous 1KB loads).
// Output written to qwh in offK (Q-frag) tiling for flash8.
__global__ __launch_bounds__(256, 2) void gemm8(const _Float16* __restrict__ xK,
                                                const _Float16* __restrict__ WT,
                                                _Float16* __restrict__ qwh) {
    const int tid = threadIdx.x;
    const int w = tid >> 6, lane = tid & 63;
    const int r31 = lane & 31, hi = lane >> 5;
    const int laneoff = (r31 << 4) + (hi << 3);
    const int blk = blockIdx.x;
    const int nb = blk & 3;
    const int mb = blk >> 2;                 // 0..127, 128 m-rows each
    const int n0w = nb * 128 + w * 32;
    const int batch = mb >> 4;
    const int mt0 = (mb & 15) * 4;           // first 32-row tile index in batch
    const size_t bb = (size_t)batch * (S_ * D_);

    // B resident: 32 k-chunks of W^T for this wave's n-tile.
    half8 Bf[32];
    const _Float16* wb = WT + ((n0w >> 5) << 14) + laneoff;
#pragma unroll
    for (int kc = 0; kc < 32; ++kc) Bf[kc] = *(const half8*)(wb + (kc << 9));

    const _Float16* ab = xK + bb + laneoff;
    const int kk = n0w + r31;
    const int qterm = (((kk >> 7) & 3) << 12) + (((kk >> 4) & 7) << 9) +
                      (((kk >> 3) & 1) << 3) + (kk & 7);

#pragma unroll
    for (int mt = 0; mt < 4; ++mt) {
        const _Float16* at = ab + ((mt0 + mt) << 14);
        f32x16 ca, cb;
#pragma unroll
        for (int r = 0; r < 16; ++r) { ca[r] = 0.f; cb[r] = 0.f; }
#pragma unroll
        for (int kg = 0; kg < 4; ++kg) {
            half8 Af[8];
#pragma unroll
            for (int k8 = 0; k8 < 8; ++k8)
                Af[k8] = *(const half8*)(at + ((kg * 8 + k8) << 9));
#pragma unroll
            for (int k8 = 0; k8 < 8; k8 += 2) {
                ca = __builtin_amdgcn_mfma_f32_32x32x16_f16(Af[k8],     Bf[kg * 8 + k8],     ca, 0, 0, 0);
                cb = __builtin_amdgcn_mfma_f32_32x32x16_f16(Af[k8 + 1], Bf[kg * 8 + k8 + 1], cb, 0, 0, 0);
            }
        }
        _Float16* qp = qwh + bb + ((mt0 + mt) << 14) + qterm;
#pragma unroll
        for (int r = 0; r < 16; ++r) {
            int mrow = (r & 3) + ((r >> 2) << 3) + (hi << 2);
            qp[mrow << 4] = (_Float16)((ca[r] + cb[r]) * INV_SCALE);
        }
    }
}

// ================= flash8: frag-tiled global loads, r=1 QK, 4-way exchange ==
// flash7 skeleton (verified): 4 waves, TQ=32, TK=32, 512 blocks (b=bx&7 one
// batch per XCD). Wave w: k-quarter w*128 of QK + d-range w*128 of PV.
// ALL global loads are contiguous 1KB wave-loads from frag-tiled buffers:
// Q/K from offK tiling, V^T from offV tiling. K reg ping-pong 1 tile ahead;
// V loaded current-tile. S partials via double-buffered conflict-free LDS,
// ONE barrier/tile. Softmax lane-local (defer-max THR=8).
__global__ __launch_bounds__(256, 2)
void flash8(const _Float16* __restrict__ xK, const _Float16* __restrict__ xV,
            const _Float16* __restrict__ qwh, float* __restrict__ out) {
    __shared__ __align__(16) unsigned char SMEM[69632];
    float* Sx = (float*)SMEM;

    const int tid = threadIdx.x;
    const int w = tid >> 6, lane = tid & 63;
    const int r31 = lane & 31, hi = lane >> 5;
    const int laneoff = (r31 << 4) + (hi << 3);
    const int d0w = w * 128;
    const int bx = blockIdx.x;
    const int b = bx & 7;
    const int q0 = (bx >> 3) * 32;
    const size_t xb = (size_t)b * (S_ * D_);

    // Q B-frags for this wave's k-quarter (contiguous 1KB each).
    half8 Qr[8];
    {
        const _Float16* qb = qwh + xb + ((q0 >> 5) << 14) + (w << 12) + laneoff;
#pragma unroll
        for (int kc = 0; kc < 8; ++kc)
            Qr[kc] = *(const half8*)(qb + (kc << 9));
    }

    const _Float16* kbase = xK + xb + (w << 12) + laneoff;
    const _Float16* vbase = xV + xb + (w << 12) + laneoff;

    // Prologue: K frags for tile 0.
    half8 Ka[8], Kb2[8];
#pragma unroll
    for (int kc = 0; kc < 8; ++kc)
        Ka[kc] = *(const half8*)(kbase + (kc << 9));

    f32x16 O[4];
#pragma unroll
    for (int dc = 0; dc < 4; ++dc)
#pragma unroll
        for (int r = 0; r < 16; ++r) O[dc][r] = 0.f;
    float m = -1e30f, l = 0.f;

#define FBODY(TI, KC, KN) do {                                                  \
    const int tc_ = (TI);                                                       \
    const int tn_ = ((TI) + 1) & 63;                                            \
    const int p_ = (TI) & 1;                                                    \
    /* current-tile V^T A-frags: contiguous 1KB loads */                        \
    half8 Vc[8];                                                                \
    _Pragma("unroll") for (int dc = 0; dc < 4; ++dc)                            \
    _Pragma("unroll") for (int kh = 0; kh < 2; ++kh)                            \
        Vc[dc * 2 + kh] = *(const half8*)(vbase + (tc_ << 14) + (dc << 10) + (kh << 9)); \
    /* QK partial (k-quarter): 8 MFMA, 2 chains */                              \
    f32x16 sa, sb;                                                              \
    _Pragma("unroll") for (int r = 0; r < 16; ++r) { sa[r] = 0.f; sb[r] = 0.f; }\
    _Pragma("unroll") for (int kc = 0; kc < 8; kc += 2) {                       \
        sa = __builtin_amdgcn_mfma_f32_32x32x16_f16(KC[kc],     Qr[kc],     sa, 0, 0, 0); \
        sb = __builtin_amdgcn_mfma_f32_32x32x16_f16(KC[kc + 1], Qr[kc + 1], sb, 0, 0, 0); \
    }                                                                           \
    /* prefetch next tile's K frags (contiguous 1KB) */                         \
    _Pragma("unroll") for (int kc = 0; kc < 8; ++kc)                            \
        KN[kc] = *(const half8*)(kbase + (tn_ << 14) + (kc << 9));              \
    f32x16 sS = sa + sb;                                                        \
    /* write partial S: contiguous 1KB per instr — conflict-free */             \
    {                                                                           \
        float* sxw = Sx + (p_ * 4 + w) * 1024;                                  \
        _Pragma("unroll") for (int r2 = 0; r2 < 4; ++r2) {                      \
            f32x4 v_ = { sS[4 * r2 + 0], sS[4 * r2 + 1], sS[4 * r2 + 2], sS[4 * r2 + 3] }; \
            *(f32x4*)&sxw[(r2 * 64 + lane) * 4] = v_;                           \
        }                                                                       \
    }                                                                           \
    __syncthreads();  /* the ONLY barrier: partials visible */                  \
    /* 4-way sum */                                                             \
    float sv[16];                                                               \
    _Pragma("unroll") for (int i = 0; i < 16; ++i) sv[i] = sS[i];               \
    _Pragma("unroll") for (int pw = 1; pw < 4; ++pw) {                          \
        const float* sxp = Sx + (p_ * 4 + (w ^ pw)) * 1024;                     \
        _Pragma("unroll") for (int r2 = 0; r2 < 4; ++r2) {                      \
            f32x4 pp = *(const f32x4*)&sxp[(r2 * 64 + lane) * 4];               \
            _Pragma("unroll") for (int j = 0; j < 4; ++j) sv[4 * r2 + j] += pp[j]; \
        }                                                                       \
    }                                                                           \
    /* lane-local online softmax (defer-max THR=8) */                           \
    float mt_ = sv[0];                                                          \
    _Pragma("unroll") for (int i = 1; i < 16; ++i) mt_ = fmaxf(mt_, sv[i]);     \
    mt_ = fmaxf(mt_, __shfl_xor(mt_, 32));                                      \
    if (__any(mt_ > m + 8.f)) {                                                 \
        float mn = fmaxf(m, mt_);                                               \
        float a_ = __expf(m - mn);                                              \
        l *= a_;                                                                \
        _Pragma("unroll") for (int dc = 0; dc < 4; ++dc)                        \
        _Pragma("unroll") for (int r = 0; r < 16; ++r) O[dc][r] *= a_;          \
        m = mn;                                                                 \
    }                                                                           \
    float pa[16]; float rs = 0.f;                                               \
    _Pragma("unroll") for (int i = 0; i < 16; ++i) { pa[i] = __expf(sv[i] - m); rs += pa[i]; } \
    l += rs + __shfl_xor(rs, 32);                                               \
    /* build PV B-frags: P[q][t=16kh+8hi+j] via cvt_pk + shfl_xor32 */          \
    u32 q16[8];                                                                 \
    _Pragma("unroll") for (int r2 = 0; r2 < 4; ++r2) {                          \
        q16[2 * r2 + 0] = pk16(pa[4 * r2 + 0], pa[4 * r2 + 1]);                 \
        q16[2 * r2 + 1] = pk16(pa[4 * r2 + 2], pa[4 * r2 + 3]);                 \
    }                                                                           \
    half8 Pf[2];                                                                \
    _Pragma("unroll") for (int kh = 0; kh < 2; ++kh) {                          \
        int r2o = 2 * kh + hi, r2s = 2 * kh + (hi ^ 1);                         \
        u32 rv0 = (u32)__shfl_xor((int)q16[2 * r2s + 0], 32);                   \
        u32 rv1 = (u32)__shfl_xor((int)q16[2 * r2s + 1], 32);                   \
        u32 o0 = q16[2 * r2o + 0], o1 = q16[2 * r2o + 1];                       \
        union { u32 u[4]; half8 v; } U_;                                        \
        U_.u[0] = hi ? rv0 : o0; U_.u[1] = hi ? rv1 : o1;                       \
        U_.u[2] = hi ? o0 : rv0; U_.u[3] = hi ? o1 : rv1;                       \
        Pf[kh] = U_.v;                                                          \
    }                                                                           \
    /* PV: O^T[d,q] += V^T x P^T */                                             \
    _Pragma("unroll") for (int dc = 0; dc < 4; ++dc) {                          \
        O[dc] = __builtin_amdgcn_mfma_f32_32x32x16_f16(Vc[dc * 2 + 0], Pf[0], O[dc], 0, 0, 0); \
        O[dc] = __builtin_amdgcn_mfma_f32_32x32x16_f16(Vc[dc * 2 + 1], Pf[1], O[dc], 0, 0, 0); \
    }                                                                           \
} while (0)

    for (int tp = 0; tp < 32; ++tp) {
        FBODY(2 * tp,     Ka,  Kb2);
        FBODY(2 * tp + 1, Kb2, Ka);
    }
#undef FBODY

    __syncthreads();   // protect Sx region before epilogue overlay

    // ---- epilogue: O^T/l -> LDS transpose -> coalesced f32x4 stores ----
    {
        float inv = 1.0f / l;
        float* ew = (float*)SMEM + w * 4224;   // 32 rows x 132 (pad) per wave
#pragma unroll
        for (int dc = 0; dc < 4; ++dc)
#pragma unroll
            for (int r = 0; r < 16; ++r) {
                int dl = dc * 32 + (r & 3) + ((r >> 2) << 3) + (hi << 2);
                ew[r31 * 132 + dl] = O[dc][r] * inv;
            }
#pragma unroll
        for (int j = 0; j < 4; ++j) {
            int flat = j * 64 + lane;
            int qq = flat >> 3, c16 = (flat & 7) << 4;
            float* gp = out + xb + (size_t)(q0 + qq) * 512 + d0w + c16;
#pragma unroll
            for (int k = 0; k < 4; ++k)
                *(f32x4*)(gp + k * 4) = *(const f32x4*)&ew[qq * 132 + c16 + k * 4];
        }
    }
}

// ================= fp32 fallback (round 1) ==================================
__global__ __launch_bounds__(256) void xw_gemm_f32(const float* __restrict__ A,
                                                   const float* __restrict__ W,
                                                   float* __restrict__ C) {
    __shared__ float As[16][65];
    __shared__ float Bs[16][64];
    const int tid = threadIdx.x;
    const int row0 = blockIdx.y * 64, col0 = blockIdx.x * 64;
    const int ty = tid / 16, tx = tid % 16;
    float acc[4][4] = {};
    const int ar = tid / 4, ak = (tid % 4) * 4, bk = tid / 16, bn = (tid % 16) * 4;
    for (int k0 = 0; k0 < 512; k0 += 16) {
        float4 a4 = *(const float4*)(A + (size_t)(row0 + ar) * 512 + k0 + ak);
        float4 b4 = *(const float4*)(W + (size_t)(k0 + bk) * 512 + col0 + bn);
        __syncthreads();
        As[ak + 0][ar] = a4.x; As[ak + 1][ar] = a4.y;
        As[ak + 2][ar] = a4.z; As[ak + 3][ar] = a4.w;
        *(float4*)&Bs[bk][bn] = b4;
        __syncthreads();
#pragma unroll
        for (int kk = 0; kk < 16; kk++) {
            float a[4], bv[4];
#pragma unroll
            for (int i = 0; i < 4; i++) a[i] = As[kk][ty * 4 + i];
#pragma unroll
            for (int j = 0; j < 4; j++) bv[j] = Bs[kk][tx * 4 + j];
#pragma unroll
            for (int i = 0; i < 4; i++)
#pragma unroll
                for (int j = 0; j < 4; j++) acc[i][j] += a[i] * bv[j];
        }
    }
#pragma unroll
    for (int i = 0; i < 4; i++) {
        float4 o = make_float4(acc[i][0] * INV_SCALE, acc[i][1] * INV_SCALE,
                               acc[i][2] * INV_SCALE, acc[i][3] * INV_SCALE);
        *(float4*)(C + (size_t)(row0 + ty * 4 + i) * 512 + col0 + tx * 4) = o;
    }
}

__global__ __launch_bounds__(256) void flash_f32(const float* __restrict__ x,
                                                 const float* __restrict__ qw,
                                                 float* __restrict__ out) {
    __shared__ float4 kt[16 * 136];
    const int tid = threadIdx.x;
    const int q = tid >> 3, g = tid & 7;
    const int blk = blockIdx.x;
    const int b = blk >> 6;
    const int qrow = (blk & 63) * 32 + q;
    const size_t xbase = (size_t)b * S_ * D_;
    float qwr[64];
    {
        const float4* p = (const float4*)(qw + xbase + (size_t)qrow * D_ + g * 64);
#pragma unroll
        for (int i4 = 0; i4 < 16; i4++) {
            float4 v = p[i4];
            qwr[4 * i4 + 0] = v.x; qwr[4 * i4 + 1] = v.y;
            qwr[4 * i4 + 2] = v.z; qwr[4 * i4 + 3] = v.w;
        }
    }
    float oa[64];
#pragma unroll
    for (int i = 0; i < 64; i++) oa[i] = 0.f;
    float m = -1e30f, l = 0.f;
    const float4* x4 = (const float4*)(x + xbase);
    for (int t0 = 0; t0 < S_; t0 += 16) {
        __syncthreads();
#pragma unroll
        for (int j = 0; j < 8; j++) {
            int f = tid + j * 256;
            int tt = f >> 7, c = f & 127;
            kt[tt * 136 + (c >> 4) * 17 + (c & 15)] = x4[(size_t)(t0 + tt) * 128 + c];
        }
        __syncthreads();
#pragma unroll 1
        for (int tt = 0; tt < 16; tt++) {
            float4 kv[16];
            const float4* kp = &kt[tt * 136 + g * 17];
#pragma unroll
            for (int i4 = 0; i4 < 16; i4++) kv[i4] = kp[i4];
            float s = 0.f;
#pragma unroll
            for (int i4 = 0; i4 < 16; i4++)
                s += qwr[4 * i4] * kv[i4].x + qwr[4 * i4 + 1] * kv[i4].y
                   + qwr[4 * i4 + 2] * kv[i4].z + qwr[4 * i4 + 3] * kv[i4].w;
            s += __shfl_xor(s, 1, 64); s += __shfl_xor(s, 2, 64); s += __shfl_xor(s, 4, 64);
            if (s > m) {
                float alpha = __expf(m - s);
                l *= alpha;
#pragma unroll
                for (int i = 0; i < 64; i++) oa[i] *= alpha;
                m = s;
            }
            float p = __expf(s - m);
            l += p;
#pragma unroll
            for (int i4 = 0; i4 < 16; i4++) {
                oa[4 * i4 + 0] += p * kv[i4].x; oa[4 * i4 + 1] += p * kv[i4].y;
                oa[4 * i4 + 2] += p * kv[i4].z; oa[4 * i4 + 3] += p * kv[i4].w;
            }
        }
    }
    float inv_l = 1.0f / l;
    float4* op = (float4*)(out + xbase + (size_t)qrow * D_ + g * 64);
#pragma unroll
    for (int i4 = 0; i4 < 16; i4++)
        op[i4] = make_float4(oa[4 * i4] * inv_l, oa[4 * i4 + 1] * inv_l,
                             oa[4 * i4 + 2] * inv_l, oa[4 * i4 + 3] * inv_l);
}

// ================= launch ====================================================
extern "C" void kernel_launch(void* const* d_in, const int* in_sizes, int n_in,
                              void* d_out, int out_size, void* d_ws, size_t ws_size,
                              hipStream_t stream) {
    const float* x = (const float*)d_in[0];
    const float* W = (const float*)d_in[1];
    float* out = (float*)d_out;

    const size_t F16 = (size_t)HSZ * sizeof(_Float16);     // 16,777,216
    const size_t off_qwh = 0;
    const size_t off_xK  = F16;
    const size_t off_xV  = 2 * F16;
    const size_t off_WT  = 3 * F16;
    const size_t base    = 3 * F16 + 512 * 512 * sizeof(_Float16);   // 50,855,936

    if (ws_size >= base) {
        _Float16* qwh = (_Float16*)((char*)d_ws + off_qwh);
        _Float16* xK  = (_Float16*)((char*)d_ws + off_xK);
        _Float16* xV  = (_Float16*)((char*)d_ws + off_xV);
        _Float16* WT  = (_Float16*)((char*)d_ws + off_WT);

        cvt_all<<<2112, 256, 0, stream>>>(x, W, xK, xV, WT);
        gemm8<<<512, 256, 0, stream>>>(xK, WT, qwh);
        flash8<<<512, 256, 0, stream>>>(xK, xV, qwh, out);
    } else {
        const size_t needf = (size_t)HSZ * sizeof(float);
        float* xw = (ws_size >= needf) ? (float*)d_ws : out;
        dim3 g1(512 / 64, (B_ * S_) / 64);
        xw_gemm_f32<<<g1, 256, 0, stream>>>(x, W, xw);
        flash_f32<<<B_ * (S_ / 32), 256, 0, stream>>>(x, xw, out);
    }
}